// Round 6
// baseline (537.506 us; speedup 1.0000x reference)
//
#include <hip/hip_runtime.h>
#include <stdint.h>

// ---------------------------------------------------------------------------
// LUT-quantized AlexNet on MI355X — f64 pre-quant numerics (absmax 0.0).
// R11 = R9 base (proven 470us) + R10's k_wmax fix + A/B experiment:
//  - L1/L2: R9 k_conv (f64 LUT, b64 gather, 1 gather/MAC) — proven.
//  - L3/L4: k_convP pair-f64 LUT (64KB LDS): one ds_read_b128 feeds TWO
//    accumulators (0.5 LDS-instr/MAC, no cvt, same bank pattern).
//    Distinguish in counters via LDS_Block_Size (5.6KB vs ~69KB).
// ---------------------------------------------------------------------------

#define DI __device__ __forceinline__

constexpr size_t alup(size_t x){ return (x + 511) & ~(size_t)511; }
constexpr size_t O_SLOTS = 0;                            // 16 doubles
constexpr size_t O_IA0 = 512;                            // 24576 u8
constexpr size_t O_IA5 = alup(O_IA0 + 24576);            // 32768 (uint2[4096])
constexpr size_t O_IA6 = alup(O_IA5 + 32768);            // 32768
constexpr size_t O_IA7 = alup(O_IA6 + 32768);            // 32768
constexpr size_t O_WP0 = alup(O_IA7 + 32768);            // 864
constexpr size_t O_WP1 = alup(O_WP0 + 864);              // 55296
constexpr size_t O_WP2 = alup(O_WP1 + 55296);            // 331776
constexpr size_t O_WP3 = alup(O_WP2 + 331776);           // 442368
constexpr size_t O_WP4 = alup(O_WP3 + 442368);           // 294912
constexpr size_t O_A1  = alup(O_WP4 + 294912);           // 131072 f64
constexpr size_t O_A2  = alup(O_A1 + 1048576);           // 98304 f64
constexpr size_t O_A3  = alup(O_A2 + 786432);            // 196608 f64
constexpr size_t O_A4  = alup(O_A3 + 1572864);           // 131072 f64
constexpr size_t O_A5  = alup(O_A4 + 1048576);           // 32768 f64
constexpr size_t O_H5  = alup(O_A5 + 262144);            // 32768 f64
constexpr size_t O_H6  = alup(O_H5 + 262144);            // 32768 f64
constexpr size_t O_P1  = alup(O_H6 + 262144);            // [8,192,16,16] f64
constexpr size_t O_P2  = O_P1 + 3145728;                 // [8,384,8,8] f64
constexpr size_t O_P3  = O_P2 + 1572864;                 // [8,256,8,8] f64
constexpr size_t O_P4  = O_P3 + 1048576;                 // [8,256,8,8] f64
constexpr int    PZ_D4 = 212992;                         // total P doubles / 4

// slots(double): [0..7]=absmax(w0..w7), [8]=absmax(x), [9..15]=absmax act 1..7

DI double getscale(const double* slots, int i){ return fmax(slots[i] / 7.0, 1e-8); }
DI int quant_idx_r(double v, double r){ // r = 1/s
  double q = fmin(fmax(rint(v * r), -8.0), 7.0);
  return (int)q + 8;
}
DI void atomicMaxD(double* addr, double v){ // v >= 0
  atomicMax((unsigned long long*)addr, (unsigned long long)__double_as_longlong(v));
}

// zero slots + all P buffers in one launch
__global__ __launch_bounds__(256) void k_zero_all(double4* pz, double* slots){
  int i = blockIdx.x*256 + threadIdx.x;
  if (i < PZ_D4){ double4 z; z.x=z.y=z.z=z.w=0.0; pz[i] = z; }
  else if (i - PZ_D4 < 16) slots[i - PZ_D4] = 0.0;
}

DI float fmax4(float4 v){
  return fmaxf(fmaxf(fabsf(v.x), fabsf(v.y)), fmaxf(fabsf(v.z), fabsf(v.w)));
}

__global__ __launch_bounds__(256) void k_wmax(
    const float* w0, const float* w1, const float* w2, const float* w3, const float* w4,
    const float* w5, const float* w6, const float* w7, const float* x, double* slots)
{
  const int sizes[9] = {1728,110592,663552,884736,589824,16777216,16777216,40960,24576};
  const int cum[10]  = {0,1,5,26,53,71,583,1095,1097,1098};
  int bid = blockIdx.x;
  int seg = 0;
  #pragma unroll
  for (int s2 = 0; s2 < 9; ++s2) if (bid >= cum[s2+1]) seg = s2+1;
  const float* p;
  switch (seg){
    case 0: p = w0; break; case 1: p = w1; break; case 2: p = w2; break;
    case 3: p = w3; break; case 4: p = w4; break; case 5: p = w5; break;
    case 6: p = w6; break; case 7: p = w7; break; default: p = x; break;
  }
  long n = sizes[seg];
  long base = (long)(bid - cum[seg]) * 32768;
  long lim = n < base + 32768 ? n : base + 32768;
  long i = base + threadIdx.x * 4;
  float m0 = 0.f, m1 = 0.f, m2 = 0.f, m3 = 0.f;
  // 4-deep batch: 4 independent loads in flight (latency-bound fix)
  for (; i + 3076 <= lim; i += 4096){
    float4 v0 = *(const float4*)(p + i);
    float4 v1 = *(const float4*)(p + i + 1024);
    float4 v2 = *(const float4*)(p + i + 2048);
    float4 v3 = *(const float4*)(p + i + 3072);
    m0 = fmaxf(m0, fmax4(v0)); m1 = fmaxf(m1, fmax4(v1));
    m2 = fmaxf(m2, fmax4(v2)); m3 = fmaxf(m3, fmax4(v3));
  }
  for (; i < lim; i += 1024) m0 = fmaxf(m0, fmax4(*(const float4*)(p + i)));
  float m = fmaxf(fmaxf(m0, m1), fmaxf(m2, m3));
  #pragma unroll
  for (int off = 32; off; off >>= 1) m = fmaxf(m, __shfl_xor(m, off, 64));
  __shared__ float red[4];
  if ((threadIdx.x & 63) == 0) red[threadIdx.x >> 6] = m;
  __syncthreads();
  if (threadIdx.x == 0)
    atomicMaxD(&slots[seg], (double)fmaxf(fmaxf(red[0], red[1]), fmaxf(red[2], red[3])));
}

// quantize conv weights (nibble-packed, nibble j = o%8) and x (byte-packed).
__global__ __launch_bounds__(256) void k_wq(
    const float* w0, const float* w1, const float* w2, const float* w3, const float* w4,
    const float* x, const double* slots, uint8_t* ws)
{
  int item = blockIdx.x * 256 + threadIdx.x;
  if (item < 281304){
    const float* w; uint32_t* wp; int K; int r; double s;
    if (item < 216)        { w=w0; wp=(uint32_t*)(ws+O_WP0); K=27;   r=item;        s=getscale(slots,0); }
    else if (item < 14040) { w=w1; wp=(uint32_t*)(ws+O_WP1); K=576;  r=item-216;    s=getscale(slots,1); }
    else if (item < 96984) { w=w2; wp=(uint32_t*)(ws+O_WP2); K=1728; r=item-14040;  s=getscale(slots,2); }
    else if (item < 207576){ w=w3; wp=(uint32_t*)(ws+O_WP3); K=3456; r=item-96984;  s=getscale(slots,3); }
    else                   { w=w4; wp=(uint32_t*)(ws+O_WP4); K=2304; r=item-207576; s=getscale(slots,4); }
    double rs = 1.0 / s;
    int og = r / K, k = r % K;
    uint32_t pack = 0;
    #pragma unroll
    for (int j = 0; j < 8; ++j){
      double wv = (double)w[(size_t)(og*8 + j)*K + k];
      pack |= (uint32_t)quant_idx_r(wv, rs) << (4*j);
    }
    wp[og*K + k] = pack;
  } else if (item < 287448){
    int i2 = item - 281304;
    double rs = 1.0 / getscale(slots, 8);
    uint32_t pack = 0;
    #pragma unroll
    for (int r2 = 0; r2 < 4; ++r2)
      pack |= (uint32_t)quant_idx_r((double)x[i2*4 + r2], rs) << (8*r2);
    ((uint32_t*)(ws + O_IA0))[i2] = pack;
  }
}

// conv0: direct (C=3,K=27), fused relu+maxpool+absmax. grid 512 = 8b x 64o,
// 1024 threads = 1 conv px each; 2x2 pool via shfl_xor(1)/(32).
__global__ __launch_bounds__(1024) void k_conv0(
    const uint8_t* __restrict__ ia0, const uint32_t* __restrict__ wp0,
    const float* __restrict__ lut_g, const float* __restrict__ bias,
    double* slots, double* __restrict__ a1)
{
  __shared__ double lutT[256];  // [iw][ia] f64
  __shared__ uint8_t acts[3*34*34];
  __shared__ double red[16];
  int tid = threadIdx.x;
  if (tid < 256) lutT[(tid & 15)*16 + (tid >> 4)] = (double)lut_g[tid];
  int b = blockIdx.x >> 6, o = blockIdx.x & 63;
  for (int i = tid; i < 3*34*34; i += 1024){
    int c = i / 1156, r = (i / 34) % 34, cc = i % 34;
    int y = r - 1, x2 = cc - 1;
    uint8_t v = 8;
    if (y >= 0 && y < 32 && x2 >= 0 && x2 < 32)
      v = ia0[((b*3 + c)*32 + y)*32 + x2];
    acts[i] = v;
  }
  __syncthreads();
  int y = tid >> 5, x2 = tid & 31;
  double scale = getscale(slots, 8) * getscale(slots, 0);
  double bo = (double)bias[o];
  double sum = 0.0;
  #pragma unroll
  for (int c = 0; c < 3; ++c)
    #pragma unroll
    for (int ty = 0; ty < 3; ++ty)
      #pragma unroll
      for (int tx = 0; tx < 3; ++tx){
        int ia = acts[c*1156 + (y + ty)*34 + (x2 + tx)];
        uint32_t sw = wp0[(o >> 3)*27 + c*9 + ty*3 + tx];
        int iw = (sw >> ((o & 7)*4)) & 15;
        sum += lutT[iw*16 + ia];
      }
  double h = fmax(sum*scale + bo, 0.0);
  // 2x2 maxpool across lanes: x-pair via xor 1, y-pair via xor 32
  double p = fmax(h, __shfl_xor(h, 1, 64));
  p = fmax(p, __shfl_xor(p, 32, 64));
  if (!(x2 & 1) && !(y & 1))
    a1[((b*64 + o)*16 + (y >> 1))*16 + (x2 >> 1)] = p;
  // absmax (pool output max == conv relu max)
  double m = h;
  #pragma unroll
  for (int off = 32; off; off >>= 1) m = fmax(m, __shfl_xor(m, off, 64));
  if ((tid & 63) == 0) red[tid >> 6] = m;
  __syncthreads();
  if (tid == 0){
    double mm = red[0];
    #pragma unroll
    for (int w2 = 1; w2 < 16; ++w2) mm = fmax(mm, red[w2]);
    atomicMaxD(&slots[9], mm);
  }
}

// generic 3x3 conv (R9-proven). Block = 4 waves = 4 output-groups (32 outs),
// one k-slice. f64 LDS LUT gather (ds_read_b64), tv[9] batch, acts ia<<3.
template<int C, int O, int H, int W, int CT, int ROWS, int SP, int KS>
__global__ __launch_bounds__(256, 8) void k_conv(
    const double* __restrict__ ain, const uint32_t* __restrict__ wp,
    const float* __restrict__ lut_g, const double* __restrict__ slots,
    int sx_slot, double* __restrict__ P)
{
  constexpr int KT = CT*9;
  constexpr int AW = W + 2, AH = ROWS + 2;
  __shared__ double lutT[256];                   // [iw][ia] f64, 2KB
  __shared__ alignas(16) uint32_t wps[4*CT*12];  // [wave][ct][12] padded rows
  __shared__ uint8_t acts[CT*AH*AW];             // pre-shifted (ia<<3)
  int tid = threadIdx.x;
  int bx = blockIdx.x;
  int ks = bx % KS; int rem = bx / KS;
  int ob = rem % (O/32); rem /= (O/32);
  int sp = rem % SP; int b = rem / SP;
  lutT[(tid & 15)*16 + (tid >> 4)] = (double)lut_g[tid];
  for (int i = tid; i < 4*KT; i += 256){
    int w2 = i / KT, k = i % KT;
    wps[(w2*CT + k/9)*12 + (k%9)] = wp[(size_t)(ob*4 + w2)*(C*9) + (size_t)ks*KT + k];
  }
  double rsx = 1.0 / getscale(slots, sx_slot);
  for (int i = tid; i < CT*AH*AW; i += 256){
    int ct = i / (AH*AW);
    int r  = (i / AW) % AH;
    int cc = i % AW;
    int y = sp*ROWS + r - 1, x2 = cc - 1;
    int v = 8;  // zero-pad -> quant level 0 -> idx 8 (still contributes!)
    if (y >= 0 && y < H && x2 >= 0 && x2 < W)
      v = quant_idx_r(ain[(((size_t)b*C + ks*CT + ct)*H + y)*W + x2], rsx);
    acts[i] = (uint8_t)(v << 3);
  }
  __syncthreads();
  int wid = tid >> 6, lane = tid & 63;
  int ly = lane / W, lx = lane % W;
  double acc[8] = {0,0,0,0,0,0,0,0};
  const char* lutB = (const char*)lutT;
  #pragma unroll 1
  for (int ct = 0; ct < CT; ++ct){
    int abase = (ct*AH + ly)*AW + lx;
    const uint32_t* wr2 = &wps[(wid*CT + ct)*12];
    uint4 wa = *(const uint4*)(wr2);
    uint4 wb = *(const uint4*)(wr2 + 4);
    uint32_t wc = wr2[8];
    uint32_t wv[9] = {wa.x, wa.y, wa.z, wa.w, wb.x, wb.y, wb.z, wb.w, wc};
    uint32_t sw[9];
    #pragma unroll
    for (int t = 0; t < 9; ++t)
      sw[t] = (uint32_t)__builtin_amdgcn_readfirstlane((int)wv[t]);
    uint32_t ia8[9];
    #pragma unroll
    for (int t = 0; t < 9; ++t)
      ia8[t] = acts[abase + (t/3)*AW + (t%3)];
    #pragma unroll
    for (int j = 0; j < 8; ++j){
      double tv[9];
      #pragma unroll
      for (int t = 0; t < 9; ++t)
        tv[t] = *(const double*)(lutB + (((sw[t] >> (4*j)) & 15u) << 7) + ia8[t]);
      #pragma unroll
      for (int t = 0; t < 9; ++t) acc[j] += tv[t];
    }
  }
  int y = sp*ROWS + ly;
  int obase = ob*32 + wid*8;
  #pragma unroll
  for (int j = 0; j < 8; ++j)
    atomicAdd(&P[(((size_t)b*O + obase + j)*H + y)*W + lx], acc[j]);
}

// EXPERIMENT: pair-f64 conv. lutP[pairbyte][ia] = double2{lut[lo],lut[hi]}
// (64KB LDS, 2 blocks/CU). One ds_read_b128 feeds acc[2bj] AND acc[2bj+1]:
// 0.5 LDS instr/MAC, zero cvt. addr = pair<<8 | ia<<4 -> same bank pattern
// as the proven f64 LUT (<=2-way). Per-acc add order (ct,t) identical.
template<int C, int O, int H, int W, int CT, int ROWS, int SP, int KS>
__global__ __launch_bounds__(256, 2) void k_convP(
    const double* __restrict__ ain, const uint32_t* __restrict__ wp,
    const float* __restrict__ lut_g, const double* __restrict__ slots,
    int sx_slot, double* __restrict__ P)
{
  constexpr int KT = CT*9;
  constexpr int AW = W + 2, AH = ROWS + 2;
  __shared__ double2 lutP[4096];                 // [pair][ia], 64KB
  __shared__ alignas(16) uint32_t wps[4*CT*12];
  __shared__ uint8_t acts[CT*AH*AW];             // pre-shifted (ia<<4)
  int tid = threadIdx.x;
  int bx = blockIdx.x;
  int ks = bx % KS; int rem = bx / KS;
  int ob = rem % (O/32); rem /= (O/32);
  int sp = rem % SP; int b = rem / SP;
  for (int i = tid; i < 4096; i += 256){
    int pr = i >> 4, ia = i & 15;
    lutP[i] = make_double2((double)lut_g[ia*16 + (pr & 15)],
                           (double)lut_g[ia*16 + (pr >> 4)]);
  }
  for (int i = tid; i < 4*KT; i += 256){
    int w2 = i / KT, k = i % KT;
    wps[(w2*CT + k/9)*12 + (k%9)] = wp[(size_t)(ob*4 + w2)*(C*9) + (size_t)ks*KT + k];
  }
  double rsx = 1.0 / getscale(slots, sx_slot);
  for (int i = tid; i < CT*AH*AW; i += 256){
    int ct = i / (AH*AW);
    int r  = (i / AW) % AH;
    int cc = i % AW;
    int y = sp*ROWS + r - 1, x2 = cc - 1;
    int v = 8;
    if (y >= 0 && y < H && x2 >= 0 && x2 < W)
      v = quant_idx_r(ain[(((size_t)b*C + ks*CT + ct)*H + y)*W + x2], rsx);
    acts[i] = (uint8_t)(v << 4);
  }
  __syncthreads();
  int wid = tid >> 6, lane = tid & 63;
  int ly = lane / W, lx = lane % W;
  double acc[8] = {0,0,0,0,0,0,0,0};
  const char* lutB = (const char*)lutP;
  #pragma unroll 1
  for (int ct = 0; ct < CT; ++ct){
    int abase = (ct*AH + ly)*AW + lx;
    const uint32_t* wr2 = &wps[(wid*CT + ct)*12];
    uint4 wa = *(const uint4*)(wr2);
    uint4 wb = *(const uint4*)(wr2 + 4);
    uint32_t wc = wr2[8];
    uint32_t wv[9] = {wa.x, wa.y, wa.z, wa.w, wb.x, wb.y, wb.z, wb.w, wc};
    uint32_t sw[9];
    #pragma unroll
    for (int t = 0; t < 9; ++t)
      sw[t] = (uint32_t)__builtin_amdgcn_readfirstlane((int)wv[t]);
    uint32_t ia16[9];
    #pragma unroll
    for (int t = 0; t < 9; ++t)
      ia16[t] = acts[abase + (t/3)*AW + (t%3)];
    #pragma unroll
    for (int bj = 0; bj < 4; ++bj){
      double2 tv[9];
      #pragma unroll
      for (int t = 0; t < 9; ++t)
        tv[t] = *(const double2*)(lutB + (((sw[t] >> (8*bj)) & 255u) << 8) + ia16[t]);
      #pragma unroll
      for (int t = 0; t < 9; ++t){
        acc[2*bj]   += tv[t].x;
        acc[2*bj+1] += tv[t].y;
      }
    }
  }
  int y = sp*ROWS + ly;
  int obase = ob*32 + wid*8;
  #pragma unroll
  for (int j = 0; j < 8; ++j)
    atomicAdd(&P[(((size_t)b*O + obase + j)*H + y)*W + lx], acc[j]);
}

// P + bias + relu (+pool) + write act f64 + absmax.
template<int O, int Hc, int Wc, bool POOL>
__global__ __launch_bounds__(256) void k_post(
    const double* __restrict__ P, const float* __restrict__ bias,
    double* __restrict__ aout, double* slots, int sx_slot, int sw_slot, int ma_slot)
{
  constexpr int Ho = POOL ? Hc/2 : Hc, Wo = POOL ? Wc/2 : Wc;
  int i = blockIdx.x*256 + threadIdx.x;
  int x2 = i % Wo, y = (i / Wo) % Ho, o = (i / (Wo*Ho)) % O, b = i / (Wo*Ho*O);
  double scale = getscale(slots, sx_slot) * getscale(slots, sw_slot);
  double bo = (double)bias[o];
  double res;
  if (POOL){
    double p = 0.0;
    #pragma unroll
    for (int dy = 0; dy < 2; ++dy)
    #pragma unroll
    for (int dx = 0; dx < 2; ++dx){
      double s = P[(((size_t)b*O + o)*Hc + y*2+dy)*Wc + x2*2+dx];
      p = fmax(p, fmax(s*scale + bo, 0.0));
    }
    res = p;
  } else {
    double s = P[(((size_t)b*O + o)*Hc + y)*Wc + x2];
    res = fmax(s*scale + bo, 0.0);
  }
  aout[i] = res;
  double m = res;
  #pragma unroll
  for (int off = 32; off; off >>= 1) m = fmax(m, __shfl_xor(m, off, 64));
  __shared__ double red[4];
  if ((threadIdx.x & 63) == 0) red[threadIdx.x >> 6] = m;
  __syncthreads();
  if (threadIdx.x == 0)
    atomicMaxD(&slots[ma_slot], fmax(fmax(red[0],red[1]), fmax(red[2],red[3])));
}

// fc-input quant: [b][4096] f64 -> per-f uint2 {lo: b0..3, hi: b4..7},
// bytes hold (idx<<2) so they are direct f32-LUT byte offsets.
__global__ __launch_bounds__(256) void k_aq_fc(
    const double* __restrict__ in, uint2* __restrict__ lh,
    const double* slots, int slot)
{
  int f = blockIdx.x*256 + threadIdx.x; // 4096
  double rs = 1.0 / getscale(slots, slot);
  uint32_t l = 0, h = 0;
  #pragma unroll
  for (int b2 = 0; b2 < 4; ++b2)
    l |= (uint32_t)(quant_idx_r(in[(size_t)b2*4096 + f], rs) << 2) << (8*b2);
  #pragma unroll
  for (int b2 = 4; b2 < 8; ++b2)
    h |= (uint32_t)(quant_idx_r(in[(size_t)b2*4096 + f], rs) << 2) << (8*(b2-4));
  lh[f] = make_uint2(l, h);
}

// fc 4096->4096, 1 output/wave, f32 LDS LUT, on-the-fly weight quant.
template<bool RELU>
__global__ __launch_bounds__(256) void k_fc(
    const float* __restrict__ Wm, const float* __restrict__ bias,
    const uint2* __restrict__ lh_g, const float* __restrict__ lut_g,
    double* __restrict__ out, double* slots, int sx_slot, int sw_slot, int ma_slot)
{
  __shared__ float lutT[256];   // [iw][ia]
  __shared__ uint2 lhs[4096];
  __shared__ double red[4];
  int tid = threadIdx.x;
  lutT[(tid & 15)*16 + (tid >> 4)] = lut_g[tid];
  for (int i = tid; i < 4096; i += 256) lhs[i] = lh_g[i];
  __syncthreads();
  double sw = getscale(slots, sw_slot);
  double rsw = 1.0 / sw;
  double scale = getscale(slots, sx_slot) * sw;
  int wid = tid >> 6, lane = tid & 63;
  int o = blockIdx.x*4 + wid;
  const float* wr = Wm + (size_t)o*4096;
  double acc[8] = {0,0,0,0,0,0,0,0};
  #pragma unroll 2
  for (int ch = 0; ch < 64; ++ch){
    int f = ch*64 + lane;
    unsigned iw = (unsigned)quant_idx_r((double)wr[f], rsw);
    const char* lb = (const char*)lutT + (iw << 6);
    uint2 lh = lhs[f];
    acc[0] += (double)*(const float*)(lb + (lh.x & 255u));
    acc[1] += (double)*(const float*)(lb + ((lh.x >> 8) & 255u));
    acc[2] += (double)*(const float*)(lb + ((lh.x >> 16) & 255u));
    acc[3] += (double)*(const float*)(lb + (lh.x >> 24));
    acc[4] += (double)*(const float*)(lb + (lh.y & 255u));
    acc[5] += (double)*(const float*)(lb + ((lh.y >> 8) & 255u));
    acc[6] += (double)*(const float*)(lb + ((lh.y >> 16) & 255u));
    acc[7] += (double)*(const float*)(lb + (lh.y >> 24));
  }
  #pragma unroll
  for (int off = 32; off; off >>= 1)
    #pragma unroll
    for (int b2 = 0; b2 < 8; ++b2) acc[b2] += __shfl_xor(acc[b2], off, 64);
  if (lane == 0){
    double m = 0.0;
    double bo = (double)bias[o];
    #pragma unroll
    for (int b2 = 0; b2 < 8; ++b2){
      double h = acc[b2]*scale + bo;
      if (RELU) h = fmax(h, 0.0);
      out[(size_t)b2*4096 + o] = h;
      m = fmax(m, fabs(h));
    }
    red[wid] = m;
  }
  __syncthreads();
  if (tid == 0)
    atomicMaxD(&slots[ma_slot], fmax(fmax(red[0],red[1]), fmax(red[2],red[3])));
}

// final fc 4096->10 (no relu), writes d_out [8,10] as f32. 1024 threads.
__global__ __launch_bounds__(1024) void k_fc7(
    const float* __restrict__ Wm, const float* __restrict__ bias,
    const uint2* __restrict__ lh_g, const float* __restrict__ lut_g,
    float* __restrict__ out, const double* slots)
{
  __shared__ float lutT[256];
  __shared__ uint2 lhs[4096];
  __shared__ double red[16][8];
  int tid = threadIdx.x;
  if (tid < 256) lutT[(tid & 15)*16 + (tid >> 4)] = lut_g[tid];
  for (int i = tid; i < 4096; i += 1024) lhs[i] = lh_g[i];
  __syncthreads();
  double sw = getscale(slots, 7);
  double rsw = 1.0 / sw;
  double scale = getscale(slots, 15) * sw;
  int o = blockIdx.x;
  const float* wr = Wm + (size_t)o*4096;
  double acc[8] = {0,0,0,0,0,0,0,0};
  #pragma unroll
  for (int ch = 0; ch < 4; ++ch){
    int f = ch*1024 + tid;
    unsigned iw = (unsigned)quant_idx_r((double)wr[f], rsw);
    const char* lb = (const char*)lutT + (iw << 6);
    uint2 lh = lhs[f];
    acc[0] += (double)*(const float*)(lb + (lh.x & 255u));
    acc[1] += (double)*(const float*)(lb + ((lh.x >> 8) & 255u));
    acc[2] += (double)*(const float*)(lb + ((lh.x >> 16) & 255u));
    acc[3] += (double)*(const float*)(lb + (lh.x >> 24));
    acc[4] += (double)*(const float*)(lb + (lh.y & 255u));
    acc[5] += (double)*(const float*)(lb + ((lh.y >> 8) & 255u));
    acc[6] += (double)*(const float*)(lb + ((lh.y >> 16) & 255u));
    acc[7] += (double)*(const float*)(lb + (lh.y >> 24));
  }
  int wid = tid >> 6, lane = tid & 63;
  #pragma unroll
  for (int off = 32; off; off >>= 1)
    #pragma unroll
    for (int b2 = 0; b2 < 8; ++b2) acc[b2] += __shfl_xor(acc[b2], off, 64);
  if (lane == 0){
    #pragma unroll
    for (int b2 = 0; b2 < 8; ++b2) red[wid][b2] = acc[b2];
  }
  __syncthreads();
  if (tid < 8){
    double v = 0.0;
    #pragma unroll
    for (int w2 = 0; w2 < 16; ++w2) v += red[w2][tid];
    out[tid*10 + o] = (float)(v*scale + (double)bias[o]);
  }
}

// ---------------- launcher ----------------
extern "C" void kernel_launch(void* const* d_in, const int* in_sizes, int n_in,
                              void* d_out, int out_size, void* d_ws, size_t ws_size,
                              hipStream_t stream)
{
  (void)in_sizes; (void)n_in; (void)out_size; (void)ws_size;
  const float* x  = (const float*)d_in[0];
  const float* w0 = (const float*)d_in[1];  const float* b0 = (const float*)d_in[2];
  const float* w1 = (const float*)d_in[3];  const float* b1 = (const float*)d_in[4];
  const float* w2 = (const float*)d_in[5];  const float* b2 = (const float*)d_in[6];
  const float* w3 = (const float*)d_in[7];  const float* b3 = (const float*)d_in[8];
  const float* w4 = (const float*)d_in[9];  const float* b4 = (const float*)d_in[10];
  const float* w5 = (const float*)d_in[11]; const float* b5 = (const float*)d_in[12];
  const float* w6 = (const float*)d_in[13]; const float* b6 = (const float*)d_in[14];
  const float* w7 = (const float*)d_in[15]; const float* b7 = (const float*)d_in[16];
  const float* luts = (const float*)d_in[17];

  uint8_t* ws = (uint8_t*)d_ws;
  double* slots = (double*)(ws + O_SLOTS);
  const uint8_t* IA0 = ws + O_IA0;
  uint2 *IA5 = (uint2*)(ws + O_IA5), *IA6 = (uint2*)(ws + O_IA6), *IA7 = (uint2*)(ws + O_IA7);
  const uint32_t* WP0 = (const uint32_t*)(ws + O_WP0);
  const uint32_t* WP1 = (const uint32_t*)(ws + O_WP1);
  const uint32_t* WP2 = (const uint32_t*)(ws + O_WP2);
  const uint32_t* WP3 = (const uint32_t*)(ws + O_WP3);
  const uint32_t* WP4 = (const uint32_t*)(ws + O_WP4);
  double *A1 = (double*)(ws + O_A1), *A2 = (double*)(ws + O_A2), *A3 = (double*)(ws + O_A3);
  double *A4 = (double*)(ws + O_A4), *A5 = (double*)(ws + O_A5);
  double *H5 = (double*)(ws + O_H5), *H6 = (double*)(ws + O_H6);
  double *P1 = (double*)(ws + O_P1), *P2 = (double*)(ws + O_P2);
  double *P3 = (double*)(ws + O_P3), *P4 = (double*)(ws + O_P4);

  k_zero_all<<<833, 256, 0, stream>>>((double4*)(ws + O_P1), slots);
  k_wmax<<<1098, 256, 0, stream>>>(w0,w1,w2,w3,w4,w5,w6,w7,x,slots);
  k_wq<<<1123, 256, 0, stream>>>(w0,w1,w2,w3,w4,x,slots,ws);

  // L0: conv(3->64,32x32)+relu+pool -> A1 [8,64,16,16] f64, absmax->slot9
  k_conv0<<<512, 1024, 0, stream>>>(IA0, WP0, luts + 0, b0, slots, A1);

  // L1: conv(64->192,16x16)+pool. R9 variant. grid 8*6*4*8=1536
  k_conv<64,192,16,16,8,4,4,8><<<1536, 256, 0, stream>>>(A1, WP1, luts + 256, slots, 9, P1);
  k_post<192,16,16,true><<<384, 256, 0, stream>>>(P1, b1, A2, slots, 9, 1, 10);

  // L2: conv(192->384,8x8). R9 variant. grid 8*12*16=1536
  k_conv<192,384,8,8,12,8,1,16><<<1536, 256, 0, stream>>>(A2, WP2, luts + 512, slots, 10, P2);
  k_post<384,8,8,false><<<768, 256, 0, stream>>>(P2, b2, A3, slots, 10, 2, 11);

  // L3: conv(384->256,8x8). PAIR variant. grid 8*8*32=2048
  k_convP<384,256,8,8,12,8,1,32><<<2048, 256, 0, stream>>>(A3, WP3, luts + 768, slots, 11, P3);
  k_post<256,8,8,false><<<512, 256, 0, stream>>>(P3, b3, A4, slots, 11, 3, 12);

  // L4: conv(256->256,8x8)+pool. PAIR variant. grid 8*8*32=2048
  k_convP<256,256,8,8,8,8,1,32><<<2048, 256, 0, stream>>>(A4, WP4, luts + 1024, slots, 12, P4);
  k_post<256,8,8,true><<<128, 256, 0, stream>>>(P4, b4, A5, slots, 12, 4, 13);
  k_aq_fc<<<16, 256, 0, stream>>>(A5, IA5, slots, 13);

  // FC
  k_fc<true><<<1024, 256, 0, stream>>>(w5, b5, IA5, luts + 1280, H5, slots, 13, 5, 14);
  k_aq_fc<<<16, 256, 0, stream>>>(H5, IA6, slots, 14);
  k_fc<true><<<1024, 256, 0, stream>>>(w6, b6, IA6, luts + 1536, H6, slots, 14, 6, 15);
  k_aq_fc<<<16, 256, 0, stream>>>(H6, IA7, slots, 15);
  k_fc7<<<10, 1024, 0, stream>>>(w7, b7, IA7, luts + 1792, (float*)d_out, slots);
}

// Round 7
// 465.316 us; speedup vs baseline: 1.1551x; 1.1551x over previous
//
#include <hip/hip_runtime.h>
#include <stdint.h>

// ---------------------------------------------------------------------------
// LUT-quantized AlexNet on MI355X — f64 pre-quant numerics (absmax 0.0).
// R12 = best-known recombination:
//  - all convs: R9 k_conv (f64 LUT, b64 gather, tv[9] batch, 8 blk/CU) —
//    proven <=48us; five alternative inner loops all regressed (R6,R7,R10,R11).
//  - k_wmax: R10 4-deep load batch (proven: left top-5).
//  - NEW: k_fc/k_fc7 4-deep batched loads (4 weight f32 + 4 lh uint2 in
//    flight) — same MLP=1 latency disease k_wmax had. Per-lane f-ascending
//    accumulate order unchanged -> bit-identical.
// ---------------------------------------------------------------------------

#define DI __device__ __forceinline__

constexpr size_t alup(size_t x){ return (x + 511) & ~(size_t)511; }
constexpr size_t O_SLOTS = 0;                            // 16 doubles
constexpr size_t O_IA0 = 512;                            // 24576 u8
constexpr size_t O_IA5 = alup(O_IA0 + 24576);            // 32768 (uint2[4096])
constexpr size_t O_IA6 = alup(O_IA5 + 32768);            // 32768
constexpr size_t O_IA7 = alup(O_IA6 + 32768);            // 32768
constexpr size_t O_WP0 = alup(O_IA7 + 32768);            // 864
constexpr size_t O_WP1 = alup(O_WP0 + 864);              // 55296
constexpr size_t O_WP2 = alup(O_WP1 + 55296);            // 331776
constexpr size_t O_WP3 = alup(O_WP2 + 331776);           // 442368
constexpr size_t O_WP4 = alup(O_WP3 + 442368);           // 294912
constexpr size_t O_A1  = alup(O_WP4 + 294912);           // 131072 f64
constexpr size_t O_A2  = alup(O_A1 + 1048576);           // 98304 f64
constexpr size_t O_A3  = alup(O_A2 + 786432);            // 196608 f64
constexpr size_t O_A4  = alup(O_A3 + 1572864);           // 131072 f64
constexpr size_t O_A5  = alup(O_A4 + 1048576);           // 32768 f64
constexpr size_t O_H5  = alup(O_A5 + 262144);            // 32768 f64
constexpr size_t O_H6  = alup(O_H5 + 262144);            // 32768 f64
constexpr size_t O_P1  = alup(O_H6 + 262144);            // [8,192,16,16] f64
constexpr size_t O_P2  = O_P1 + 3145728;                 // [8,384,8,8] f64
constexpr size_t O_P3  = O_P2 + 1572864;                 // [8,256,8,8] f64
constexpr size_t O_P4  = O_P3 + 1048576;                 // [8,256,8,8] f64
constexpr int    PZ_D4 = 212992;                         // total P doubles / 4

// slots(double): [0..7]=absmax(w0..w7), [8]=absmax(x), [9..15]=absmax act 1..7

DI double getscale(const double* slots, int i){ return fmax(slots[i] / 7.0, 1e-8); }
DI int quant_idx_r(double v, double r){ // r = 1/s
  double q = fmin(fmax(rint(v * r), -8.0), 7.0);
  return (int)q + 8;
}
DI void atomicMaxD(double* addr, double v){ // v >= 0
  atomicMax((unsigned long long*)addr, (unsigned long long)__double_as_longlong(v));
}

// zero slots + all P buffers in one launch
__global__ __launch_bounds__(256) void k_zero_all(double4* pz, double* slots){
  int i = blockIdx.x*256 + threadIdx.x;
  if (i < PZ_D4){ double4 z; z.x=z.y=z.z=z.w=0.0; pz[i] = z; }
  else if (i - PZ_D4 < 16) slots[i - PZ_D4] = 0.0;
}

DI float fmax4(float4 v){
  return fmaxf(fmaxf(fabsf(v.x), fabsf(v.y)), fmaxf(fabsf(v.z), fabsf(v.w)));
}

__global__ __launch_bounds__(256) void k_wmax(
    const float* w0, const float* w1, const float* w2, const float* w3, const float* w4,
    const float* w5, const float* w6, const float* w7, const float* x, double* slots)
{
  const int sizes[9] = {1728,110592,663552,884736,589824,16777216,16777216,40960,24576};
  const int cum[10]  = {0,1,5,26,53,71,583,1095,1097,1098};
  int bid = blockIdx.x;
  int seg = 0;
  #pragma unroll
  for (int s2 = 0; s2 < 9; ++s2) if (bid >= cum[s2+1]) seg = s2+1;
  const float* p;
  switch (seg){
    case 0: p = w0; break; case 1: p = w1; break; case 2: p = w2; break;
    case 3: p = w3; break; case 4: p = w4; break; case 5: p = w5; break;
    case 6: p = w6; break; case 7: p = w7; break; default: p = x; break;
  }
  long n = sizes[seg];
  long base = (long)(bid - cum[seg]) * 32768;
  long lim = n < base + 32768 ? n : base + 32768;
  long i = base + threadIdx.x * 4;
  float m0 = 0.f, m1 = 0.f, m2 = 0.f, m3 = 0.f;
  for (; i + 3076 <= lim; i += 4096){
    float4 v0 = *(const float4*)(p + i);
    float4 v1 = *(const float4*)(p + i + 1024);
    float4 v2 = *(const float4*)(p + i + 2048);
    float4 v3 = *(const float4*)(p + i + 3072);
    m0 = fmaxf(m0, fmax4(v0)); m1 = fmaxf(m1, fmax4(v1));
    m2 = fmaxf(m2, fmax4(v2)); m3 = fmaxf(m3, fmax4(v3));
  }
  for (; i < lim; i += 1024) m0 = fmaxf(m0, fmax4(*(const float4*)(p + i)));
  float m = fmaxf(fmaxf(m0, m1), fmaxf(m2, m3));
  #pragma unroll
  for (int off = 32; off; off >>= 1) m = fmaxf(m, __shfl_xor(m, off, 64));
  __shared__ float red[4];
  if ((threadIdx.x & 63) == 0) red[threadIdx.x >> 6] = m;
  __syncthreads();
  if (threadIdx.x == 0)
    atomicMaxD(&slots[seg], (double)fmaxf(fmaxf(red[0], red[1]), fmaxf(red[2], red[3])));
}

// quantize conv weights (nibble-packed, nibble j = o%8) and x (byte-packed).
__global__ __launch_bounds__(256) void k_wq(
    const float* w0, const float* w1, const float* w2, const float* w3, const float* w4,
    const float* x, const double* slots, uint8_t* ws)
{
  int item = blockIdx.x * 256 + threadIdx.x;
  if (item < 281304){
    const float* w; uint32_t* wp; int K; int r; double s;
    if (item < 216)        { w=w0; wp=(uint32_t*)(ws+O_WP0); K=27;   r=item;        s=getscale(slots,0); }
    else if (item < 14040) { w=w1; wp=(uint32_t*)(ws+O_WP1); K=576;  r=item-216;    s=getscale(slots,1); }
    else if (item < 96984) { w=w2; wp=(uint32_t*)(ws+O_WP2); K=1728; r=item-14040;  s=getscale(slots,2); }
    else if (item < 207576){ w=w3; wp=(uint32_t*)(ws+O_WP3); K=3456; r=item-96984;  s=getscale(slots,3); }
    else                   { w=w4; wp=(uint32_t*)(ws+O_WP4); K=2304; r=item-207576; s=getscale(slots,4); }
    double rs = 1.0 / s;
    int og = r / K, k = r % K;
    uint32_t pack = 0;
    #pragma unroll
    for (int j = 0; j < 8; ++j){
      double wv = (double)w[(size_t)(og*8 + j)*K + k];
      pack |= (uint32_t)quant_idx_r(wv, rs) << (4*j);
    }
    wp[og*K + k] = pack;
  } else if (item < 287448){
    int i2 = item - 281304;
    double rs = 1.0 / getscale(slots, 8);
    uint32_t pack = 0;
    #pragma unroll
    for (int r2 = 0; r2 < 4; ++r2)
      pack |= (uint32_t)quant_idx_r((double)x[i2*4 + r2], rs) << (8*r2);
    ((uint32_t*)(ws + O_IA0))[i2] = pack;
  }
}

// conv0: direct (C=3,K=27), fused relu+maxpool+absmax. grid 512 = 8b x 64o,
// 1024 threads = 1 conv px each; 2x2 pool via shfl_xor(1)/(32).
__global__ __launch_bounds__(1024) void k_conv0(
    const uint8_t* __restrict__ ia0, const uint32_t* __restrict__ wp0,
    const float* __restrict__ lut_g, const float* __restrict__ bias,
    double* slots, double* __restrict__ a1)
{
  __shared__ double lutT[256];  // [iw][ia] f64
  __shared__ uint8_t acts[3*34*34];
  __shared__ double red[16];
  int tid = threadIdx.x;
  if (tid < 256) lutT[(tid & 15)*16 + (tid >> 4)] = (double)lut_g[tid];
  int b = blockIdx.x >> 6, o = blockIdx.x & 63;
  for (int i = tid; i < 3*34*34; i += 1024){
    int c = i / 1156, r = (i / 34) % 34, cc = i % 34;
    int y = r - 1, x2 = cc - 1;
    uint8_t v = 8;
    if (y >= 0 && y < 32 && x2 >= 0 && x2 < 32)
      v = ia0[((b*3 + c)*32 + y)*32 + x2];
    acts[i] = v;
  }
  __syncthreads();
  int y = tid >> 5, x2 = tid & 31;
  double scale = getscale(slots, 8) * getscale(slots, 0);
  double bo = (double)bias[o];
  double sum = 0.0;
  #pragma unroll
  for (int c = 0; c < 3; ++c)
    #pragma unroll
    for (int ty = 0; ty < 3; ++ty)
      #pragma unroll
      for (int tx = 0; tx < 3; ++tx){
        int ia = acts[c*1156 + (y + ty)*34 + (x2 + tx)];
        uint32_t sw = wp0[(o >> 3)*27 + c*9 + ty*3 + tx];
        int iw = (sw >> ((o & 7)*4)) & 15;
        sum += lutT[iw*16 + ia];
      }
  double h = fmax(sum*scale + bo, 0.0);
  double p = fmax(h, __shfl_xor(h, 1, 64));
  p = fmax(p, __shfl_xor(p, 32, 64));
  if (!(x2 & 1) && !(y & 1))
    a1[((b*64 + o)*16 + (y >> 1))*16 + (x2 >> 1)] = p;
  double m = h;
  #pragma unroll
  for (int off = 32; off; off >>= 1) m = fmax(m, __shfl_xor(m, off, 64));
  if ((tid & 63) == 0) red[tid >> 6] = m;
  __syncthreads();
  if (tid == 0){
    double mm = red[0];
    #pragma unroll
    for (int w2 = 1; w2 < 16; ++w2) mm = fmax(mm, red[w2]);
    atomicMaxD(&slots[9], mm);
  }
}

// generic 3x3 conv (R9-proven). Block = 4 waves = 4 output-groups (32 outs),
// one k-slice. f64 LDS LUT gather (ds_read_b64), tv[9] batch, acts ia<<3.
template<int C, int O, int H, int W, int CT, int ROWS, int SP, int KS>
__global__ __launch_bounds__(256, 8) void k_conv(
    const double* __restrict__ ain, const uint32_t* __restrict__ wp,
    const float* __restrict__ lut_g, const double* __restrict__ slots,
    int sx_slot, double* __restrict__ P)
{
  constexpr int KT = CT*9;
  constexpr int AW = W + 2, AH = ROWS + 2;
  __shared__ double lutT[256];                   // [iw][ia] f64, 2KB
  __shared__ alignas(16) uint32_t wps[4*CT*12];  // [wave][ct][12] padded rows
  __shared__ uint8_t acts[CT*AH*AW];             // pre-shifted (ia<<3)
  int tid = threadIdx.x;
  int bx = blockIdx.x;
  int ks = bx % KS; int rem = bx / KS;
  int ob = rem % (O/32); rem /= (O/32);
  int sp = rem % SP; int b = rem / SP;
  lutT[(tid & 15)*16 + (tid >> 4)] = (double)lut_g[tid];
  for (int i = tid; i < 4*KT; i += 256){
    int w2 = i / KT, k = i % KT;
    wps[(w2*CT + k/9)*12 + (k%9)] = wp[(size_t)(ob*4 + w2)*(C*9) + (size_t)ks*KT + k];
  }
  double rsx = 1.0 / getscale(slots, sx_slot);
  for (int i = tid; i < CT*AH*AW; i += 256){
    int ct = i / (AH*AW);
    int r  = (i / AW) % AH;
    int cc = i % AW;
    int y = sp*ROWS + r - 1, x2 = cc - 1;
    int v = 8;  // zero-pad -> quant level 0 -> idx 8 (still contributes!)
    if (y >= 0 && y < H && x2 >= 0 && x2 < W)
      v = quant_idx_r(ain[(((size_t)b*C + ks*CT + ct)*H + y)*W + x2], rsx);
    acts[i] = (uint8_t)(v << 3);
  }
  __syncthreads();
  int wid = tid >> 6, lane = tid & 63;
  int ly = lane / W, lx = lane % W;
  double acc[8] = {0,0,0,0,0,0,0,0};
  const char* lutB = (const char*)lutT;
  #pragma unroll 1
  for (int ct = 0; ct < CT; ++ct){
    int abase = (ct*AH + ly)*AW + lx;
    const uint32_t* wr2 = &wps[(wid*CT + ct)*12];
    uint4 wa = *(const uint4*)(wr2);
    uint4 wb = *(const uint4*)(wr2 + 4);
    uint32_t wc = wr2[8];
    uint32_t wv[9] = {wa.x, wa.y, wa.z, wa.w, wb.x, wb.y, wb.z, wb.w, wc};
    uint32_t sw[9];
    #pragma unroll
    for (int t = 0; t < 9; ++t)
      sw[t] = (uint32_t)__builtin_amdgcn_readfirstlane((int)wv[t]);
    uint32_t ia8[9];
    #pragma unroll
    for (int t = 0; t < 9; ++t)
      ia8[t] = acts[abase + (t/3)*AW + (t%3)];
    #pragma unroll
    for (int j = 0; j < 8; ++j){
      double tv[9];
      #pragma unroll
      for (int t = 0; t < 9; ++t)
        tv[t] = *(const double*)(lutB + (((sw[t] >> (4*j)) & 15u) << 7) + ia8[t]);
      #pragma unroll
      for (int t = 0; t < 9; ++t) acc[j] += tv[t];
    }
  }
  int y = sp*ROWS + ly;
  int obase = ob*32 + wid*8;
  #pragma unroll
  for (int j = 0; j < 8; ++j)
    atomicAdd(&P[(((size_t)b*O + obase + j)*H + y)*W + lx], acc[j]);
}

// P + bias + relu (+pool) + write act f64 + absmax.
template<int O, int Hc, int Wc, bool POOL>
__global__ __launch_bounds__(256) void k_post(
    const double* __restrict__ P, const float* __restrict__ bias,
    double* __restrict__ aout, double* slots, int sx_slot, int sw_slot, int ma_slot)
{
  constexpr int Ho = POOL ? Hc/2 : Hc, Wo = POOL ? Wc/2 : Wc;
  int i = blockIdx.x*256 + threadIdx.x;
  int x2 = i % Wo, y = (i / Wo) % Ho, o = (i / (Wo*Ho)) % O, b = i / (Wo*Ho*O);
  double scale = getscale(slots, sx_slot) * getscale(slots, sw_slot);
  double bo = (double)bias[o];
  double res;
  if (POOL){
    double p = 0.0;
    #pragma unroll
    for (int dy = 0; dy < 2; ++dy)
    #pragma unroll
    for (int dx = 0; dx < 2; ++dx){
      double s = P[(((size_t)b*O + o)*Hc + y*2+dy)*Wc + x2*2+dx];
      p = fmax(p, fmax(s*scale + bo, 0.0));
    }
    res = p;
  } else {
    double s = P[(((size_t)b*O + o)*Hc + y)*Wc + x2];
    res = fmax(s*scale + bo, 0.0);
  }
  aout[i] = res;
  double m = res;
  #pragma unroll
  for (int off = 32; off; off >>= 1) m = fmax(m, __shfl_xor(m, off, 64));
  __shared__ double red[4];
  if ((threadIdx.x & 63) == 0) red[threadIdx.x >> 6] = m;
  __syncthreads();
  if (threadIdx.x == 0)
    atomicMaxD(&slots[ma_slot], fmax(fmax(red[0],red[1]), fmax(red[2],red[3])));
}

// fc-input quant: [b][4096] f64 -> per-f uint2 {lo: b0..3, hi: b4..7},
// bytes hold (idx<<2) so they are direct f32-LUT byte offsets.
__global__ __launch_bounds__(256) void k_aq_fc(
    const double* __restrict__ in, uint2* __restrict__ lh,
    const double* slots, int slot)
{
  int f = blockIdx.x*256 + threadIdx.x; // 4096
  double rs = 1.0 / getscale(slots, slot);
  uint32_t l = 0, h = 0;
  #pragma unroll
  for (int b2 = 0; b2 < 4; ++b2)
    l |= (uint32_t)(quant_idx_r(in[(size_t)b2*4096 + f], rs) << 2) << (8*b2);
  #pragma unroll
  for (int b2 = 4; b2 < 8; ++b2)
    h |= (uint32_t)(quant_idx_r(in[(size_t)b2*4096 + f], rs) << 2) << (8*(b2-4));
  lh[f] = make_uint2(l, h);
}

DI void fc_tap(double* acc, const char* lutT, unsigned iw, uint2 lh){
  const char* lb = lutT + (iw << 6);
  acc[0] += (double)*(const float*)(lb + (lh.x & 255u));
  acc[1] += (double)*(const float*)(lb + ((lh.x >> 8) & 255u));
  acc[2] += (double)*(const float*)(lb + ((lh.x >> 16) & 255u));
  acc[3] += (double)*(const float*)(lb + (lh.x >> 24));
  acc[4] += (double)*(const float*)(lb + (lh.y & 255u));
  acc[5] += (double)*(const float*)(lb + ((lh.y >> 8) & 255u));
  acc[6] += (double)*(const float*)(lb + ((lh.y >> 16) & 255u));
  acc[7] += (double)*(const float*)(lb + (lh.y >> 24));
}

// fc 4096->4096, 1 output/wave, f32 LDS LUT, on-the-fly weight quant.
// 4-deep batched loads (4 w + 4 lh in flight); f-ascending acc order kept.
template<bool RELU>
__global__ __launch_bounds__(256) void k_fc(
    const float* __restrict__ Wm, const float* __restrict__ bias,
    const uint2* __restrict__ lh_g, const float* __restrict__ lut_g,
    double* __restrict__ out, double* slots, int sx_slot, int sw_slot, int ma_slot)
{
  __shared__ float lutT[256];   // [iw][ia]
  __shared__ uint2 lhs[4096];
  __shared__ double red[4];
  int tid = threadIdx.x;
  lutT[(tid & 15)*16 + (tid >> 4)] = lut_g[tid];
  for (int i = tid; i < 4096; i += 256) lhs[i] = lh_g[i];
  __syncthreads();
  double sw = getscale(slots, sw_slot);
  double rsw = 1.0 / sw;
  double scale = getscale(slots, sx_slot) * sw;
  int wid = tid >> 6, lane = tid & 63;
  int o = blockIdx.x*4 + wid;
  const float* wr = Wm + (size_t)o*4096;
  double acc[8] = {0,0,0,0,0,0,0,0};
  #pragma unroll 1
  for (int ch = 0; ch < 16; ++ch){
    int f = ch*256 + lane;
    float w0v = wr[f], w1v = wr[f+64], w2v = wr[f+128], w3v = wr[f+192];
    uint2 lh0 = lhs[f], lh1 = lhs[f+64], lh2 = lhs[f+128], lh3 = lhs[f+192];
    unsigned iw0 = (unsigned)quant_idx_r((double)w0v, rsw);
    unsigned iw1 = (unsigned)quant_idx_r((double)w1v, rsw);
    unsigned iw2 = (unsigned)quant_idx_r((double)w2v, rsw);
    unsigned iw3 = (unsigned)quant_idx_r((double)w3v, rsw);
    fc_tap(acc, (const char*)lutT, iw0, lh0);
    fc_tap(acc, (const char*)lutT, iw1, lh1);
    fc_tap(acc, (const char*)lutT, iw2, lh2);
    fc_tap(acc, (const char*)lutT, iw3, lh3);
  }
  #pragma unroll
  for (int off = 32; off; off >>= 1)
    #pragma unroll
    for (int b2 = 0; b2 < 8; ++b2) acc[b2] += __shfl_xor(acc[b2], off, 64);
  if (lane == 0){
    double m = 0.0;
    double bo = (double)bias[o];
    #pragma unroll
    for (int b2 = 0; b2 < 8; ++b2){
      double h = acc[b2]*scale + bo;
      if (RELU) h = fmax(h, 0.0);
      out[(size_t)b2*4096 + o] = h;
      m = fmax(m, fabs(h));
    }
    red[wid] = m;
  }
  __syncthreads();
  if (tid == 0)
    atomicMaxD(&slots[ma_slot], fmax(fmax(red[0],red[1]), fmax(red[2],red[3])));
}

// final fc 4096->10 (no relu), writes d_out [8,10] as f32. 1024 threads,
// 4-deep batched loads.
__global__ __launch_bounds__(1024) void k_fc7(
    const float* __restrict__ Wm, const float* __restrict__ bias,
    const uint2* __restrict__ lh_g, const float* __restrict__ lut_g,
    float* __restrict__ out, const double* slots)
{
  __shared__ float lutT[256];
  __shared__ uint2 lhs[4096];
  __shared__ double red[16][8];
  int tid = threadIdx.x;
  if (tid < 256) lutT[(tid & 15)*16 + (tid >> 4)] = lut_g[tid];
  for (int i = tid; i < 4096; i += 1024) lhs[i] = lh_g[i];
  __syncthreads();
  double sw = getscale(slots, 7);
  double rsw = 1.0 / sw;
  double scale = getscale(slots, 15) * sw;
  int o = blockIdx.x;
  const float* wr = Wm + (size_t)o*4096;
  double acc[8] = {0,0,0,0,0,0,0,0};
  {
    float w0v = wr[tid], w1v = wr[tid+1024], w2v = wr[tid+2048], w3v = wr[tid+3072];
    uint2 lh0 = lhs[tid], lh1 = lhs[tid+1024], lh2 = lhs[tid+2048], lh3 = lhs[tid+3072];
    unsigned iw0 = (unsigned)quant_idx_r((double)w0v, rsw);
    unsigned iw1 = (unsigned)quant_idx_r((double)w1v, rsw);
    unsigned iw2 = (unsigned)quant_idx_r((double)w2v, rsw);
    unsigned iw3 = (unsigned)quant_idx_r((double)w3v, rsw);
    fc_tap(acc, (const char*)lutT, iw0, lh0);
    fc_tap(acc, (const char*)lutT, iw1, lh1);
    fc_tap(acc, (const char*)lutT, iw2, lh2);
    fc_tap(acc, (const char*)lutT, iw3, lh3);
  }
  int wid = tid >> 6, lane = tid & 63;
  #pragma unroll
  for (int off = 32; off; off >>= 1)
    #pragma unroll
    for (int b2 = 0; b2 < 8; ++b2) acc[b2] += __shfl_xor(acc[b2], off, 64);
  if (lane == 0){
    #pragma unroll
    for (int b2 = 0; b2 < 8; ++b2) red[wid][b2] = acc[b2];
  }
  __syncthreads();
  if (tid < 8){
    double v = 0.0;
    #pragma unroll
    for (int w2 = 0; w2 < 16; ++w2) v += red[w2][tid];
    out[tid*10 + o] = (float)(v*scale + (double)bias[o]);
  }
}

// ---------------- launcher ----------------
extern "C" void kernel_launch(void* const* d_in, const int* in_sizes, int n_in,
                              void* d_out, int out_size, void* d_ws, size_t ws_size,
                              hipStream_t stream)
{
  (void)in_sizes; (void)n_in; (void)out_size; (void)ws_size;
  const float* x  = (const float*)d_in[0];
  const float* w0 = (const float*)d_in[1];  const float* b0 = (const float*)d_in[2];
  const float* w1 = (const float*)d_in[3];  const float* b1 = (const float*)d_in[4];
  const float* w2 = (const float*)d_in[5];  const float* b2 = (const float*)d_in[6];
  const float* w3 = (const float*)d_in[7];  const float* b3 = (const float*)d_in[8];
  const float* w4 = (const float*)d_in[9];  const float* b4 = (const float*)d_in[10];
  const float* w5 = (const float*)d_in[11]; const float* b5 = (const float*)d_in[12];
  const float* w6 = (const float*)d_in[13]; const float* b6 = (const float*)d_in[14];
  const float* w7 = (const float*)d_in[15]; const float* b7 = (const float*)d_in[16];
  const float* luts = (const float*)d_in[17];

  uint8_t* ws = (uint8_t*)d_ws;
  double* slots = (double*)(ws + O_SLOTS);
  const uint8_t* IA0 = ws + O_IA0;
  uint2 *IA5 = (uint2*)(ws + O_IA5), *IA6 = (uint2*)(ws + O_IA6), *IA7 = (uint2*)(ws + O_IA7);
  const uint32_t* WP0 = (const uint32_t*)(ws + O_WP0);
  const uint32_t* WP1 = (const uint32_t*)(ws + O_WP1);
  const uint32_t* WP2 = (const uint32_t*)(ws + O_WP2);
  const uint32_t* WP3 = (const uint32_t*)(ws + O_WP3);
  const uint32_t* WP4 = (const uint32_t*)(ws + O_WP4);
  double *A1 = (double*)(ws + O_A1), *A2 = (double*)(ws + O_A2), *A3 = (double*)(ws + O_A3);
  double *A4 = (double*)(ws + O_A4), *A5 = (double*)(ws + O_A5);
  double *H5 = (double*)(ws + O_H5), *H6 = (double*)(ws + O_H6);
  double *P1 = (double*)(ws + O_P1), *P2 = (double*)(ws + O_P2);
  double *P3 = (double*)(ws + O_P3), *P4 = (double*)(ws + O_P4);

  k_zero_all<<<833, 256, 0, stream>>>((double4*)(ws + O_P1), slots);
  k_wmax<<<1098, 256, 0, stream>>>(w0,w1,w2,w3,w4,w5,w6,w7,x,slots);
  k_wq<<<1123, 256, 0, stream>>>(w0,w1,w2,w3,w4,x,slots,ws);

  // L0: conv(3->64,32x32)+relu+pool -> A1 [8,64,16,16] f64, absmax->slot9
  k_conv0<<<512, 1024, 0, stream>>>(IA0, WP0, luts + 0, b0, slots, A1);

  // L1: conv(64->192,16x16)+pool. grid 8*6*4*8=1536
  k_conv<64,192,16,16,8,4,4,8><<<1536, 256, 0, stream>>>(A1, WP1, luts + 256, slots, 9, P1);
  k_post<192,16,16,true><<<384, 256, 0, stream>>>(P1, b1, A2, slots, 9, 1, 10);

  // L2: conv(192->384,8x8). grid 8*12*16=1536
  k_conv<192,384,8,8,12,8,1,16><<<1536, 256, 0, stream>>>(A2, WP2, luts + 512, slots, 10, P2);
  k_post<384,8,8,false><<<768, 256, 0, stream>>>(P2, b2, A3, slots, 10, 2, 11);

  // L3: conv(384->256,8x8). grid 8*8*32=2048
  k_conv<384,256,8,8,12,8,1,32><<<2048, 256, 0, stream>>>(A3, WP3, luts + 768, slots, 11, P3);
  k_post<256,8,8,false><<<512, 256, 0, stream>>>(P3, b3, A4, slots, 11, 3, 12);

  // L4: conv(256->256,8x8)+pool. grid 8*8*32=2048
  k_conv<256,256,8,8,8,8,1,32><<<2048, 256, 0, stream>>>(A4, WP4, luts + 1024, slots, 12, P4);
  k_post<256,8,8,true><<<128, 256, 0, stream>>>(P4, b4, A5, slots, 12, 4, 13);
  k_aq_fc<<<16, 256, 0, stream>>>(A5, IA5, slots, 13);

  // FC
  k_fc<true><<<1024, 256, 0, stream>>>(w5, b5, IA5, luts + 1280, H5, slots, 13, 5, 14);
  k_aq_fc<<<16, 256, 0, stream>>>(H5, IA6, slots, 14);
  k_fc<true><<<1024, 256, 0, stream>>>(w6, b6, IA6, luts + 1536, H6, slots, 14, 6, 15);
  k_aq_fc<<<16, 256, 0, stream>>>(H6, IA7, slots, 15);
  k_fc7<<<10, 1024, 0, stream>>>(w7, b7, IA7, luts + 1792, (float*)d_out, slots);
}